// Round 6
// baseline (15822.247 us; speedup 1.0000x reference)
//
#include <hip/hip_runtime.h>
#include <stdint.h>

#define Bdim 4
#define Tdim 2048
#define Vdim 32000
#define Hdim 512
#define MROWS 8192
#define SENT 0xFFFFFFFFu

typedef unsigned short u16;
typedef uint32_t u32;
typedef unsigned long long u64t;
typedef __bf16 bf16x8 __attribute__((ext_vector_type(8)));
typedef float f32x4 __attribute__((ext_vector_type(4)));

__device__ __forceinline__ u16 f2bf(float f) {
  union { float f; u32 u; } a; a.f = f;
  u32 r = a.u + 0x7FFFu + ((a.u >> 16) & 1u);
  return (u16)(r >> 16);
}
__device__ __forceinline__ float unbf(u64t v, int r) {
  union { u32 u; float f; } x; x.u = ((u32)(v >> (16 * r)) & 0xFFFFu) << 16; return x.f;
}
__device__ __forceinline__ u64t pack4(float a, float b, float c, float d) {
  return (u64t)f2bf(a) | ((u64t)f2bf(b) << 16) | ((u64t)f2bf(c) << 32) | ((u64t)f2bf(d) << 48);
}
__device__ __forceinline__ u64t al64(const u64t* p) {
  return __hip_atomic_load(p, __ATOMIC_RELAXED, __HIP_MEMORY_SCOPE_AGENT);
}
__device__ __forceinline__ void as64(u64t* p, u64t v) {
  __hip_atomic_store(p, v, __ATOMIC_RELAXED, __HIP_MEMORY_SCOPE_AGENT);
}
__device__ __forceinline__ bool bad64(u64t v) {
  return ((u32)v == SENT) | ((u32)(v >> 32) == SENT);
}
__device__ __forceinline__ bf16x8 cast8(u64t a, u64t b) {
  union { u64t u[2]; bf16x8 h; } U; U.u[0] = a; U.u[1] = b; return U.h;
}
__device__ __forceinline__ float fast_tanh(float x) {
  float e = __expf(2.f * x);
  return 1.f - 2.f / (e + 1.f);
}

// ---------------- embedding gather -> bf16 ----------------
__global__ void k_gather(const int* __restrict__ x, const float* __restrict__ embed,
                         u16* __restrict__ E) {
  int idx = blockIdx.x * 256 + threadIdx.x;
  int row = idx >> 7;
  int c4  = (idx & 127) << 2;
  int tok = x[row];
  const float4 v = *(const float4*)(embed + (size_t)tok * Hdim + c4);
  *(ushort4*)(E + (size_t)row * Hdim + c4) =
      make_ushort4(f2bf(v.x), f2bf(v.y), f2bf(v.z), f2bf(v.w));
}

// ---------------- fp32 -> bf16 convert ----------------
__global__ void k_f2b(const float* __restrict__ in, u16* __restrict__ out, int n4) {
  int idx = blockIdx.x * 256 + threadIdx.x;
  if (idx >= n4) return;
  const float4 v = *(const float4*)(in + (size_t)idx * 4);
  *(ushort4*)(out + (size_t)idx * 4) =
      make_ushort4(f2bf(v.x), f2bf(v.y), f2bf(v.z), f2bf(v.w));
}

// ---------------- bf16 MFMA GEMM (X0 pre-pass): C = A @ Bw^T + b1 + b2 -------
__device__ __forceinline__ void g2l16(const void* g, void* l) {
  __builtin_amdgcn_global_load_lds(
      (const __attribute__((address_space(1))) u32*)g,
      (__attribute__((address_space(3))) u32*)l, 16, 0, 0);
}

__global__ __launch_bounds__(256, 2) void k_gemm(
    const u16* __restrict__ A, const u16* __restrict__ Bw, void* __restrict__ Cv,
    const float* __restrict__ bias1, const float* __restrict__ bias2,
    int M, int N, int K, int ntN, int obf)
{
  __shared__ u16 Al[128 * 64];
  __shared__ u16 Bl[128 * 64];
  const int bid = blockIdx.x;
  const int mt = bid / ntN, nt = bid % ntN;
  const int m0 = mt << 7, n0 = nt << 7;
  const int tid = threadIdx.x;
  const int l = tid & 63, w = tid >> 6;
  const int wy = w >> 1, wx = w & 1;
  const int frow = l & 15, fk = (l >> 4) << 3;

  f32x4 acc[4][4];
  #pragma unroll
  for (int a = 0; a < 4; ++a)
    #pragma unroll
    for (int b = 0; b < 4; ++b) acc[a][b] = f32x4{0.f, 0.f, 0.f, 0.f};

  for (int kb = 0; kb < K; kb += 64) {
    __syncthreads();
    #pragma unroll
    for (int is = 0; is < 4; ++is) {
      const int off = tid * 16 + is * 4096;
      const int lrow = off >> 7, lcolB = off & 127;
      g2l16(A  + (size_t)(m0 + lrow) * K + kb + (lcolB >> 1), (char*)Al + off);
      g2l16(Bw + (size_t)(n0 + lrow) * K + kb + (lcolB >> 1), (char*)Bl + off);
    }
    __syncthreads();
    #pragma unroll
    for (int ks = 0; ks < 2; ++ks) {
      bf16x8 af[4], bfr[4];
      #pragma unroll
      for (int mi = 0; mi < 4; ++mi)
        af[mi] = *(const bf16x8*)&Al[((wy * 64 + mi * 16 + frow) << 6) + ks * 32 + fk];
      #pragma unroll
      for (int ni = 0; ni < 4; ++ni)
        bfr[ni] = *(const bf16x8*)&Bl[((wx * 64 + ni * 16 + frow) << 6) + ks * 32 + fk];
      #pragma unroll
      for (int mi = 0; mi < 4; ++mi)
        #pragma unroll
        for (int ni = 0; ni < 4; ++ni)
          acc[mi][ni] = __builtin_amdgcn_mfma_f32_16x16x32_bf16(af[mi], bfr[ni], acc[mi][ni], 0, 0, 0);
    }
  }
  #pragma unroll
  for (int ni = 0; ni < 4; ++ni) {
    const int col = n0 + wx * 64 + ni * 16 + (l & 15);
    float bv = bias1[col];
    if (bias2) bv += bias2[col];
    #pragma unroll
    for (int mi = 0; mi < 4; ++mi) {
      const int row = m0 + wy * 64 + mi * 16 + ((l >> 4) << 2);
      #pragma unroll
      for (int r = 0; r < 4; ++r) {
        const float v = acc[mi][ni][r] + bv;
        if (obf) ((u16*)Cv)[(size_t)(row + r) * N + col] = f2bf(v);
        else     ((float*)Cv)[(size_t)(row + r) * N + col] = v;
      }
    }
  }
}

// ================= persistent fused scan + out-projection ====================
// grid 252 x 512thr. Block 0: L0 recurrence (intra-CU, LDS h, weights in
// VGPR+LDS). Block 1: L1 recurrence. Blocks 2,3: X1 helpers (Wih1*h0[t]).
// Blocks 4..251: out-projection GEMM workers gated by per-step release flags.

// LDS map (bytes): [0,131072) weight frags; [131072,139520) h dbuf;
// [139520,141568) helper bias. Workers reuse [0,32768) as Al/Bl.

template <int ROLE>   // 0 = L0, 1 = L1
__device__ void rec_role(const u16* __restrict__ Wb, const u16* __restrict__ X0b,
                         u64t* __restrict__ Hself, const u64t* __restrict__ X1g,
                         u32* __restrict__ flag, float* __restrict__ hfin, char* smem)
{
  u16* wlds = (u16*)smem;
  u16* hdb  = (u16*)(smem + 131072);
  const int tid = threadIdx.x;
  const int l = tid & 63, wv = tid >> 6;
  const int nb = wv * 64;
  const int frow = l & 15, fk = (l >> 4) << 3;
  const int vb = l & 15, vg = l >> 4;
  const bool valid = vb < 4;
  const int hrow = (vb & 3) * 528;          // B-frag LDS row (u16)
  const int nvb = nb + vg * 4;

  // weights: K-blocks 0..11 in VGPRs, 12..15 in LDS (per-lane frag layout)
  bf16x8 wf[4][12];
  #pragma unroll
  for (int tl = 0; tl < 4; ++tl)
    #pragma unroll
    for (int kb = 0; kb < 12; ++kb)
      wf[tl][kb] = *(const bf16x8*)&Wb[(size_t)(nb + tl * 16 + frow) * Hdim + kb * 32 + fk];
  #pragma unroll
  for (int tl = 0; tl < 4; ++tl)
    #pragma unroll
    for (int kbl = 0; kbl < 4; ++kbl) {
      bf16x8 f = *(const bf16x8*)&Wb[(size_t)(nb + tl * 16 + frow) * Hdim + (12 + kbl) * 32 + fk];
      *(bf16x8*)&wlds[(((wv * 4 + tl) * 4 + kbl) << 9) + l * 8] = f;
    }
  for (int i = tid; i < 2112; i += 512) ((u32*)hdb)[i] = 0u;   // zero h dbufs
  __syncthreads();

  u64t x1v[4];
  if (ROLE == 1) {
    #pragma unroll
    for (int tl = 0; tl < 4; ++tl)
      x1v[tl] = al64(X1g + (((size_t)(vb & 3) * 512 + nvb + tl * 16) >> 2));
  }

  #pragma unroll 1
  for (int t = 0; t < Tdim; ++t) {
    const u16* hb = hdb + (t & 1) * 2112;
    u16* hw = hdb + ((t & 1) ^ 1) * 2112;

    u64t x0v[4];
    if (ROLE == 0) {
      #pragma unroll
      for (int tl = 0; tl < 4; ++tl)
        x0v[tl] = *(const u64t*)&X0b[(size_t)((vb & 3) * Tdim + t) * Hdim + nvb + tl * 16];
    }

    f32x4 acc[4];
    #pragma unroll
    for (int tl = 0; tl < 4; ++tl) acc[tl] = f32x4{0.f, 0.f, 0.f, 0.f};

    #pragma unroll
    for (int kb = 0; kb < 12; ++kb) {
      const bf16x8 hf = *(const bf16x8*)&hb[hrow + kb * 32 + fk];
      #pragma unroll
      for (int tl = 0; tl < 4; ++tl)
        acc[tl] = __builtin_amdgcn_mfma_f32_16x16x32_bf16(wf[tl][kb], hf, acc[tl], 0, 0, 0);
    }
    #pragma unroll
    for (int kbl = 0; kbl < 4; ++kbl) {
      const bf16x8 hf = *(const bf16x8*)&hb[hrow + (12 + kbl) * 32 + fk];
      #pragma unroll
      for (int tl = 0; tl < 4; ++tl) {
        const bf16x8 wl = *(const bf16x8*)&wlds[(((wv * 4 + tl) * 4 + kbl) << 9) + l * 8];
        acc[tl] = __builtin_amdgcn_mfma_f32_16x16x32_bf16(wl, hf, acc[tl], 0, 0, 0);
      }
    }

    if (ROLE == 1) {   // resolve X1[t] (poll issued one step earlier)
      while (true) {
        bool bad = false;
        #pragma unroll
        for (int tl = 0; tl < 4; ++tl) bad |= bad64(x1v[tl]);
        if (!bad) break;
        #pragma unroll
        for (int tl = 0; tl < 4; ++tl)
          if (bad64(x1v[tl]))
            x1v[tl] = al64(X1g + (((size_t)t * 2048 + (vb & 3) * 512 + nvb + tl * 16) >> 2));
      }
    }

    if (valid) {
      #pragma unroll
      for (int tl = 0; tl < 4; ++tl) {
        const u64t xv = (ROLE == 0) ? x0v[tl] : x1v[tl];
        const float h0 = fast_tanh(acc[tl][0] + unbf(xv, 0));
        const float h1 = fast_tanh(acc[tl][1] + unbf(xv, 1));
        const float h2 = fast_tanh(acc[tl][2] + unbf(xv, 2));
        const float h3 = fast_tanh(acc[tl][3] + unbf(xv, 3));
        const int n = nvb + tl * 16;
        const u64t pk = pack4(h0, h1, h2, h3);
        *(u64t*)&hw[vb * 528 + n] = pk;                              // next-step LDS
        as64(Hself + (((size_t)t * 2048 + vb * 512 + n) >> 2), pk);  // publish
        if (t == Tdim - 1) {
          float* hd = hfin + (ROLE ? Bdim * Hdim : 0) + vb * Hdim + n;
          hd[0] = h0; hd[1] = h1; hd[2] = h2; hd[3] = h3;
        }
      }
    }
    if (ROLE == 1) {
      if ((t & 7) == 7 && l == 0)
        __hip_atomic_store(&flag[t * 8 + wv], 1u, __ATOMIC_RELEASE, __HIP_MEMORY_SCOPE_AGENT);
      if (t + 1 < Tdim) {
        #pragma unroll
        for (int tl = 0; tl < 4; ++tl)
          x1v[tl] = al64(X1g + (((size_t)(t + 1) * 2048 + (vb & 3) * 512 + nvb + tl * 16) >> 2));
      }
    }
    asm volatile("s_waitcnt lgkmcnt(0)" ::: "memory");
    __builtin_amdgcn_s_barrier();
    asm volatile("" ::: "memory");
  }
}

// helper: X1[t] = Wih1 . h0[t] + b_ih1 + b_hh1. Weights: kb 0..7 VGPR,
// 8..11 streamed from L2, 12..15 LDS. No barriers in loop.
__device__ void helper_role(const u16* __restrict__ Wb, const float* __restrict__ bi1,
                            const float* __restrict__ bi2, const u64t* __restrict__ H0g,
                            u64t* __restrict__ X1g, int hid, char* smem)
{
  u16* wlds = (u16*)smem;
  float* blds = (float*)(smem + 139520);
  const int tid = threadIdx.x;
  const int l = tid & 63, wv = tid >> 6;
  const int nb = wv * 64;
  const int frow = l & 15, fk = (l >> 4) << 3;
  const int vb = l & 15, vg = l >> 4;
  const bool valid = vb < 4;
  const int nvb = nb + vg * 4;

  bf16x8 wf[4][8];
  #pragma unroll
  for (int tl = 0; tl < 4; ++tl)
    #pragma unroll
    for (int kb = 0; kb < 8; ++kb)
      wf[tl][kb] = *(const bf16x8*)&Wb[(size_t)(nb + tl * 16 + frow) * Hdim + kb * 32 + fk];
  #pragma unroll
  for (int tl = 0; tl < 4; ++tl)
    #pragma unroll
    for (int kbl = 0; kbl < 4; ++kbl) {
      bf16x8 f = *(const bf16x8*)&Wb[(size_t)(nb + tl * 16 + frow) * Hdim + (12 + kbl) * 32 + fk];
      *(bf16x8*)&wlds[(((wv * 4 + tl) * 4 + kbl) << 9) + l * 8] = f;
    }
  for (int i = tid; i < Hdim; i += 512) blds[i] = bi1[i] + bi2[i];
  __syncthreads();

  #pragma unroll 1
  for (int t = hid; t < Tdim; t += 2) {
    f32x4 acc[4];
    #pragma unroll
    for (int tl = 0; tl < 4; ++tl) acc[tl] = f32x4{0.f, 0.f, 0.f, 0.f};
    const size_t tb64 = ((size_t)t * 2048 + (size_t)(vb & 3) * 512) >> 2;

    #pragma unroll
    for (int q = 0; q < 4; ++q) {        // quarter-rounds of 4 K-blocks
      u64t fa[4], fb[4];
      #pragma unroll
      for (int kb = 0; kb < 4; ++kb) {
        const u64t* p = H0g + tb64 + (((q * 4 + kb) * 32 + fk) >> 2);
        fa[kb] = al64(p); fb[kb] = al64(p + 1);
      }
      while (true) {
        bool bad = false;
        #pragma unroll
        for (int kb = 0; kb < 4; ++kb) bad |= bad64(fa[kb]) | bad64(fb[kb]);
        if (!bad) break;
        #pragma unroll
        for (int kb = 0; kb < 4; ++kb) {
          const u64t* p = H0g + tb64 + (((q * 4 + kb) * 32 + fk) >> 2);
          if (bad64(fa[kb])) fa[kb] = al64(p);
          if (bad64(fb[kb])) fb[kb] = al64(p + 1);
        }
      }
      #pragma unroll
      for (int kb = 0; kb < 4; ++kb) {
        const int g = q * 4 + kb;
        const bf16x8 hf = cast8(fa[kb], fb[kb]);
        #pragma unroll
        for (int tl = 0; tl < 4; ++tl) {
          bf16x8 wt;
          if (g < 8)       wt = wf[tl][g & 7];
          else if (g < 12) wt = *(const bf16x8*)&Wb[(size_t)(nb + tl * 16 + frow) * Hdim + g * 32 + fk];
          else             wt = *(const bf16x8*)&wlds[(((wv * 4 + tl) * 4 + (g - 12)) << 9) + l * 8];
          acc[tl] = __builtin_amdgcn_mfma_f32_16x16x32_bf16(wt, hf, acc[tl], 0, 0, 0);
        }
      }
    }
    if (valid) {
      #pragma unroll
      for (int tl = 0; tl < 4; ++tl) {
        const float4 bs = *(const float4*)&blds[nvb + tl * 16];
        const u64t pk = pack4(acc[tl][0] + bs.x, acc[tl][1] + bs.y,
                              acc[tl][2] + bs.z, acc[tl][3] + bs.w);
        as64(X1g + (((size_t)t * 2048 + vb * 512 + nvb + tl * 16) >> 2), pk);
      }
    }
  }
}

// out-projection worker: 128x128 tiles of out = H1 @ Wout^T + b_out,
// t-ordered, gated on L1's release flags.
__device__ void out_worker(int wid, int nworkers, const u16* __restrict__ H1,
                           const u16* __restrict__ Bw, const float* __restrict__ bias,
                           float* __restrict__ C, const u32* __restrict__ flag, char* smem)
{
  u16* Al = (u16*)smem;
  u16* Bl = (u16*)(smem + 16384);
  const int tid = threadIdx.x;
  const int l = tid & 63, w = tid >> 6;
  const int wy = w >> 1, wx = w & 1;
  const int frow = l & 15, fk = (l >> 4) << 3;
  int prev_te = -1;

  for (int lin = wid; lin < 64 * 250; lin += nworkers) {
    const int tb = lin / 250, nt = lin % 250;
    const int b = tb >> 4, t0 = (tb & 15) << 7;
    const int m0 = tb << 7, n0 = nt << 7;
    const int te = t0 + 127;
    if (te != prev_te) {
      if (tid == 0) {
        #pragma unroll 1
        for (int w8 = 0; w8 < 8; ++w8)
          while (__hip_atomic_load(&flag[te * 8 + w8], __ATOMIC_RELAXED,
                                   __HIP_MEMORY_SCOPE_AGENT) == 0u)
            __builtin_amdgcn_s_sleep(8);
      }
      __builtin_amdgcn_fence(__ATOMIC_ACQUIRE, "agent");
      __syncthreads();
      prev_te = te;
    }
    f32x4 acc[2][4];
    #pragma unroll
    for (int mi = 0; mi < 2; ++mi)
      #pragma unroll
      for (int ni = 0; ni < 4; ++ni) acc[mi][ni] = f32x4{0.f, 0.f, 0.f, 0.f};

    for (int kb = 0; kb < Hdim; kb += 64) {
      __syncthreads();
      #pragma unroll
      for (int is = 0; is < 2; ++is) {
        const int off = tid * 16 + is * 8192;
        const int lrow = off >> 7, lcol = (off & 127) >> 1;
        g2l16(H1 + (size_t)(t0 + lrow) * 2048 + b * 512 + kb + lcol, (char*)Al + off);
        g2l16(Bw + (size_t)(n0 + lrow) * 512 + kb + lcol, (char*)Bl + off);
      }
      __syncthreads();
      #pragma unroll
      for (int ks = 0; ks < 2; ++ks) {
        bf16x8 af[2], bf[4];
        #pragma unroll
        for (int mi = 0; mi < 2; ++mi)
          af[mi] = *(const bf16x8*)&Al[((wy * 32 + mi * 16 + frow) << 6) + ks * 32 + fk];
        #pragma unroll
        for (int ni = 0; ni < 4; ++ni)
          bf[ni] = *(const bf16x8*)&Bl[((wx * 64 + ni * 16 + frow) << 6) + ks * 32 + fk];
        #pragma unroll
        for (int mi = 0; mi < 2; ++mi)
          #pragma unroll
          for (int ni = 0; ni < 4; ++ni)
            acc[mi][ni] = __builtin_amdgcn_mfma_f32_16x16x32_bf16(af[mi], bf[ni], acc[mi][ni], 0, 0, 0);
      }
    }
    __syncthreads();
    #pragma unroll
    for (int ni = 0; ni < 4; ++ni) {
      const int col = n0 + wx * 64 + ni * 16 + (l & 15);
      const float bv = bias[col];
      #pragma unroll
      for (int mi = 0; mi < 2; ++mi) {
        const int row = m0 + wy * 32 + mi * 16 + ((l >> 4) << 2);
        #pragma unroll
        for (int r = 0; r < 4; ++r)
          C[(size_t)(row + r) * Vdim + col] = acc[mi][ni][r] + bv;
      }
    }
  }
}

__global__ __launch_bounds__(512, 2) void k_scan(
    const u16* __restrict__ X0b, const u16* __restrict__ Wihb,
    const u16* __restrict__ Whhb, const float* __restrict__ b_ih,
    const float* __restrict__ b_hh, u64t* __restrict__ H0g,
    u64t* __restrict__ H1g, u64t* __restrict__ X1g, u32* __restrict__ flag,
    float* __restrict__ hfin, const u16* __restrict__ Woutb,
    const float* __restrict__ b_out, float* __restrict__ out)
{
  __shared__ __align__(16) char smem[141568];
  const int bid = blockIdx.x;
  if (bid == 0)
    rec_role<0>(Whhb, X0b, H0g, nullptr, nullptr, hfin, smem);
  else if (bid == 1)
    rec_role<1>(Whhb + Hdim * Hdim, nullptr, H1g, X1g, flag, hfin, smem);
  else if (bid < 4)
    helper_role(Wihb + Hdim * Hdim, b_ih + Hdim, b_hh + Hdim, H0g, X1g, bid - 2, smem);
  else
    out_worker(bid - 4, 248, (const u16*)H1g, Woutb, b_out, out, flag, smem);
}

// ---------------- launch ----------------
extern "C" void kernel_launch(void* const* d_in, const int* in_sizes, int n_in,
                              void* d_out, int out_size, void* d_ws, size_t ws_size,
                              hipStream_t stream)
{
  const int*   x     = (const int*)d_in[0];
  const float* embed = (const float*)d_in[1];
  const float* W_ih  = (const float*)d_in[2];
  const float* b_ih  = (const float*)d_in[3];
  const float* W_hh  = (const float*)d_in[4];
  const float* b_hh  = (const float*)d_in[5];
  const float* W_out = (const float*)d_in[6];
  const float* b_out = (const float*)d_in[7];
  float* out = (float*)d_out;

  // workspace layout (~76 MB)
  char* ws = (char*)d_ws;
  u16* E     = (u16*)ws;                                  // 8192*512
  u16* Wihb  = E + (size_t)MROWS * Hdim;                  // 2*512*512
  u16* Whhb  = Wihb + 2 * Hdim * Hdim;                    // 2*512*512
  u16* Woutb = Whhb + 2 * Hdim * Hdim;                    // 32000*512
  u16* X0b   = Woutb + (size_t)Vdim * Hdim;               // 8192*512 bf16
  u64t* H0g  = (u64t*)(X0b + (size_t)MROWS * Hdim);       // [t][b][n] bf16, 8MB
  u64t* H1g  = H0g + (size_t)Tdim * 512;
  u64t* X1g  = H1g + (size_t)Tdim * 512;
  u32*  flag = (u32*)(X1g + (size_t)Tdim * 512);          // [t][wave]

  k_gather<<<MROWS * (Hdim / 4) / 256, 256, 0, stream>>>(x, embed, E);
  k_f2b<<<(2 * Hdim * Hdim / 4) / 256, 256, 0, stream>>>(W_ih, Wihb, 2 * Hdim * Hdim / 4);
  k_f2b<<<(2 * Hdim * Hdim / 4) / 256, 256, 0, stream>>>(W_hh, Whhb, 2 * Hdim * Hdim / 4);
  k_f2b<<<((size_t)Vdim * Hdim / 4) / 256, 256, 0, stream>>>(W_out, Woutb, Vdim * Hdim / 4);

  // X0 = E @ Wih0^T + b_ih0 + b_hh0 -> bf16 [b*T+t][n]
  k_gemm<<<(MROWS / 128) * (Hdim / 128), 256, 0, stream>>>(
      E, Wihb, (void*)X0b, b_ih, b_hh, MROWS, Hdim, Hdim, Hdim / 128, 1);

  hipMemsetAsync(H0g, 0xFF, (size_t)Tdim * 2048 * 2, stream);
  hipMemsetAsync(X1g, 0xFF, (size_t)Tdim * 2048 * 2, stream);
  hipMemsetAsync(flag, 0, (size_t)Tdim * 8 * 4, stream);

  float* hfin = out + (size_t)MROWS * Vdim;
  k_scan<<<252, 512, 0, stream>>>(X0b, Wihb, Whhb, b_ih, b_hh, H0g, H1g, X1g,
                                  flag, hfin, Woutb, b_out, out);
}

// Round 7
// 7099.848 us; speedup vs baseline: 2.2285x; 2.2285x over previous
//
#include <hip/hip_runtime.h>
#include <stdint.h>

#define Bdim 4
#define Tdim 2048
#define Vdim 32000
#define Hdim 512
#define MROWS 8192
#define SENT 0xFFFFFFFFu
#define NHELP 6

typedef unsigned short u16;
typedef uint32_t u32;
typedef unsigned long long u64t;
typedef __bf16 bf16x8 __attribute__((ext_vector_type(8)));
typedef float f32x4 __attribute__((ext_vector_type(4)));

__device__ __forceinline__ u16 f2bf(float f) {
  union { float f; u32 u; } a; a.f = f;
  u32 r = a.u + 0x7FFFu + ((a.u >> 16) & 1u);
  return (u16)(r >> 16);
}
__device__ __forceinline__ float unbf(u64t v, int r) {
  union { u32 u; float f; } x; x.u = ((u32)(v >> (16 * r)) & 0xFFFFu) << 16; return x.f;
}
__device__ __forceinline__ u64t pack4(float a, float b, float c, float d) {
  return (u64t)f2bf(a) | ((u64t)f2bf(b) << 16) | ((u64t)f2bf(c) << 32) | ((u64t)f2bf(d) << 48);
}
__device__ __forceinline__ u64t al64(const u64t* p) {
  return __hip_atomic_load(p, __ATOMIC_RELAXED, __HIP_MEMORY_SCOPE_AGENT);
}
__device__ __forceinline__ void as64(u64t* p, u64t v) {
  __hip_atomic_store(p, v, __ATOMIC_RELAXED, __HIP_MEMORY_SCOPE_AGENT);
}
__device__ __forceinline__ bool bad64(u64t v) {
  return ((u32)v == SENT) | ((u32)(v >> 32) == SENT);
}
__device__ __forceinline__ bf16x8 cast8(u64t a, u64t b) {
  union { u64t u[2]; bf16x8 h; } U; U.u[0] = a; U.u[1] = b; return U.h;
}
__device__ __forceinline__ float fast_tanh(float x) {
  float e = __expf(2.f * x);
  return 1.f - 2.f / (e + 1.f);
}

// ---------------- embedding gather -> bf16 ----------------
__global__ void k_gather(const int* __restrict__ x, const float* __restrict__ embed,
                         u16* __restrict__ E) {
  int idx = blockIdx.x * 256 + threadIdx.x;
  int row = idx >> 7;
  int c4  = (idx & 127) << 2;
  int tok = x[row];
  const float4 v = *(const float4*)(embed + (size_t)tok * Hdim + c4);
  *(ushort4*)(E + (size_t)row * Hdim + c4) =
      make_ushort4(f2bf(v.x), f2bf(v.y), f2bf(v.z), f2bf(v.w));
}

// ---------------- fp32 -> bf16 convert ----------------
__global__ void k_f2b(const float* __restrict__ in, u16* __restrict__ out, int n4) {
  int idx = blockIdx.x * 256 + threadIdx.x;
  if (idx >= n4) return;
  const float4 v = *(const float4*)(in + (size_t)idx * 4);
  *(ushort4*)(out + (size_t)idx * 4) =
      make_ushort4(f2bf(v.x), f2bf(v.y), f2bf(v.z), f2bf(v.w));
}

// ---------------- bf16 MFMA GEMM: C = A @ Bw^T + b1 (+b2) ----------------
// aperm=1: A row m at u16 offset (m&2047)*2048 + (m>>11)*512 ([t][b][n] layout).
// obf=1: write bf16, else fp32.
__device__ __forceinline__ void g2l16(const void* g, void* l) {
  __builtin_amdgcn_global_load_lds(
      (const __attribute__((address_space(1))) u32*)g,
      (__attribute__((address_space(3))) u32*)l, 16, 0, 0);
}

__global__ __launch_bounds__(256, 2) void k_gemm(
    const u16* __restrict__ A, const u16* __restrict__ Bw, void* __restrict__ Cv,
    const float* __restrict__ bias1, const float* __restrict__ bias2,
    int M, int N, int K, int ntN, int aperm, int obf)
{
  __shared__ u16 Al[128 * 64];
  __shared__ u16 Bl[128 * 64];
  const int bid = blockIdx.x;
  const int mt = bid / ntN, nt = bid % ntN;
  const int m0 = mt << 7, n0 = nt << 7;
  const int tid = threadIdx.x;
  const int l = tid & 63, w = tid >> 6;
  const int wy = w >> 1, wx = w & 1;
  const int frow = l & 15, fk = (l >> 4) << 3;

  f32x4 acc[4][4];
  #pragma unroll
  for (int a = 0; a < 4; ++a)
    #pragma unroll
    for (int b = 0; b < 4; ++b) acc[a][b] = f32x4{0.f, 0.f, 0.f, 0.f};

  for (int kb = 0; kb < K; kb += 64) {
    __syncthreads();
    #pragma unroll
    for (int is = 0; is < 4; ++is) {
      const int off = tid * 16 + is * 4096;
      const int lrow = off >> 7, lcolB = off & 127;
      const int mrow = m0 + lrow;
      const size_t arow = aperm
          ? (size_t)(mrow & 2047) * 2048 + (size_t)(mrow >> 11) * 512
          : (size_t)mrow * K;
      g2l16(A  + arow + kb + (lcolB >> 1), (char*)Al + off);
      g2l16(Bw + (size_t)(n0 + lrow) * K + kb + (lcolB >> 1), (char*)Bl + off);
    }
    __syncthreads();
    #pragma unroll
    for (int ks = 0; ks < 2; ++ks) {
      bf16x8 af[4], bfr[4];
      #pragma unroll
      for (int mi = 0; mi < 4; ++mi)
        af[mi] = *(const bf16x8*)&Al[((wy * 64 + mi * 16 + frow) << 6) + ks * 32 + fk];
      #pragma unroll
      for (int ni = 0; ni < 4; ++ni)
        bfr[ni] = *(const bf16x8*)&Bl[((wx * 64 + ni * 16 + frow) << 6) + ks * 32 + fk];
      #pragma unroll
      for (int mi = 0; mi < 4; ++mi)
        #pragma unroll
        for (int ni = 0; ni < 4; ++ni)
          acc[mi][ni] = __builtin_amdgcn_mfma_f32_16x16x32_bf16(af[mi], bfr[ni], acc[mi][ni], 0, 0, 0);
    }
  }
  #pragma unroll
  for (int ni = 0; ni < 4; ++ni) {
    const int col = n0 + wx * 64 + ni * 16 + (l & 15);
    float bv = bias1[col];
    if (bias2) bv += bias2[col];
    #pragma unroll
    for (int mi = 0; mi < 4; ++mi) {
      const int row = m0 + wy * 64 + mi * 16 + ((l >> 4) << 2);
      #pragma unroll
      for (int r = 0; r < 4; ++r) {
        const float v = acc[mi][ni][r] + bv;
        if (obf) ((u16*)Cv)[(size_t)(row + r) * N + col] = f2bf(v);
        else     ((float*)Cv)[(size_t)(row + r) * N + col] = v;
      }
    }
  }
}

// ================= persistent scan: 8 blocks x 512 threads ===================
// Block 0: L0 recurrence. Block 1: L1 recurrence. Blocks 2..7: X1 helpers.
// Recurrence is intra-CU: h ping-pongs in LDS; Whh in 192 VGPR + 4 K-blocks LDS.
// Cross-CU: L0 publishes h0[t] (relaxed agent u64); helpers build
// X1[t]=Wih1.h0[t]+biases; L1 polls X1 two steps ahead (value-as-flag).

#define REC_STEP(t, XSLOT)                                                      \
  {                                                                             \
    const u16* hb = hdb + ((t) & 1) * 2112;                                     \
    u16* hw = hdb + ((((t) & 1)) ^ 1) * 2112;                                   \
    u64t x0n[4];                                                                \
    if (ROLE == 0 && valid && (t) + 1 < Tdim) {                                 \
      _Pragma("unroll")                                                         \
      for (int tl = 0; tl < 4; ++tl)                                            \
        x0n[tl] = *(const u64t*)&X0b[((size_t)vb * Tdim + (t) + 1) * Hdim + nvb + tl * 16]; \
    }                                                                           \
    f32x4 acc[4];                                                               \
    _Pragma("unroll") for (int q = 0; q < 4; ++q) acc[q] = f32x4{0.f, 0.f, 0.f, 0.f}; \
    _Pragma("unroll")                                                           \
    for (int kb = 0; kb < 12; ++kb) {                                           \
      const bf16x8 hf = *(const bf16x8*)&hb[hrow + kb * 32 + fk];               \
      _Pragma("unroll")                                                         \
      for (int tl = 0; tl < 4; ++tl)                                            \
        acc[tl] = __builtin_amdgcn_mfma_f32_16x16x32_bf16(wf[tl][kb], hf, acc[tl], 0, 0, 0); \
    }                                                                           \
    _Pragma("unroll")                                                           \
    for (int kbl = 0; kbl < 4; ++kbl) {                                         \
      const bf16x8 hf = *(const bf16x8*)&hb[hrow + (12 + kbl) * 32 + fk];       \
      _Pragma("unroll")                                                         \
      for (int tl = 0; tl < 4; ++tl) {                                          \
        const bf16x8 wl = *(const bf16x8*)&wlds[(((wv * 4 + tl) * 4 + kbl) << 9) + l * 8]; \
        acc[tl] = __builtin_amdgcn_mfma_f32_16x16x32_bf16(wl, hf, acc[tl], 0, 0, 0); \
      }                                                                         \
    }                                                                           \
    u64t xloc[4];                                                               \
    if (ROLE == 1 && valid) {                                                   \
      _Pragma("unroll")                                                         \
      for (int tl = 0; tl < 4; ++tl) {                                          \
        u64t v = XSLOT[tl];                                                     \
        const u64t* p = X1g + (((size_t)(t) * 2048 + vb * 512 + nvb + tl * 16) >> 2); \
        while (bad64(v)) v = al64(p);                                           \
        xloc[tl] = v;                                                           \
      }                                                                         \
      if ((t) + 2 < Tdim) {                                                     \
        _Pragma("unroll")                                                       \
        for (int tl = 0; tl < 4; ++tl)                                          \
          XSLOT[tl] = al64(X1g + (((size_t)((t) + 2) * 2048 + vb * 512 + nvb + tl * 16) >> 2)); \
      }                                                                         \
    }                                                                           \
    if (valid) {                                                                \
      _Pragma("unroll")                                                         \
      for (int tl = 0; tl < 4; ++tl) {                                          \
        const u64t xvv = (ROLE == 0) ? x0c[tl] : xloc[tl];                      \
        const float h0 = fast_tanh(acc[tl][0] + unbf(xvv, 0));                  \
        const float h1 = fast_tanh(acc[tl][1] + unbf(xvv, 1));                  \
        const float h2 = fast_tanh(acc[tl][2] + unbf(xvv, 2));                  \
        const float h3 = fast_tanh(acc[tl][3] + unbf(xvv, 3));                  \
        const int n = nvb + tl * 16;                                            \
        const u64t pk = pack4(h0, h1, h2, h3);                                  \
        *(u64t*)&hw[vb * 528 + n] = pk;                                         \
        as64(Hself + (((size_t)(t) * 2048 + vb * 512 + n) >> 2), pk);           \
        if ((t) == Tdim - 1) {                                                  \
          float* hd = hfin + (ROLE ? Bdim * Hdim : 0) + vb * Hdim + n;          \
          hd[0] = h0; hd[1] = h1; hd[2] = h2; hd[3] = h3;                       \
        }                                                                       \
      }                                                                         \
      if (ROLE == 0 && (t) + 1 < Tdim) {                                        \
        _Pragma("unroll") for (int tl = 0; tl < 4; ++tl) x0c[tl] = x0n[tl];     \
      }                                                                         \
    }                                                                           \
    asm volatile("s_waitcnt lgkmcnt(0)" ::: "memory");                          \
    __builtin_amdgcn_sched_barrier(0);                                          \
    __builtin_amdgcn_s_barrier();                                               \
  }

template <int ROLE>
__device__ void rec_role(const u16* __restrict__ Wb, const u16* __restrict__ X0b,
                         u64t* __restrict__ Hself, const u64t* __restrict__ X1g,
                         float* __restrict__ hfin, char* smem)
{
  u16* wlds = (u16*)smem;
  u16* hdb  = (u16*)(smem + 131072);
  const int tid = threadIdx.x;
  const int l = tid & 63, wv = tid >> 6;
  const int nb = wv * 64;
  const int frow = l & 15, fk = (l >> 4) << 3;
  const int vb = l & 15, vg = l >> 4;
  const bool valid = vb < 4;
  const int hrow = (vb & 3) * 528;
  const int nvb = nb + vg * 4;

  bf16x8 wf[4][12];
  #pragma unroll
  for (int tl = 0; tl < 4; ++tl)
    #pragma unroll
    for (int kb = 0; kb < 12; ++kb)
      wf[tl][kb] = *(const bf16x8*)&Wb[(size_t)(nb + tl * 16 + frow) * Hdim + kb * 32 + fk];
  #pragma unroll
  for (int tl = 0; tl < 4; ++tl)
    #pragma unroll
    for (int kbl = 0; kbl < 4; ++kbl) {
      bf16x8 f = *(const bf16x8*)&Wb[(size_t)(nb + tl * 16 + frow) * Hdim + (12 + kbl) * 32 + fk];
      *(bf16x8*)&wlds[(((wv * 4 + tl) * 4 + kbl) << 9) + l * 8] = f;
    }
  for (int i = tid; i < 2112; i += 512) ((u32*)hdb)[i] = 0u;
  __syncthreads();

  u64t xv[4], xw[4], x0c[4];
  if (ROLE == 1 && valid) {
    #pragma unroll
    for (int tl = 0; tl < 4; ++tl) {
      xv[tl] = al64(X1g + (((size_t)0 * 2048 + vb * 512 + nvb + tl * 16) >> 2));
      xw[tl] = al64(X1g + (((size_t)1 * 2048 + vb * 512 + nvb + tl * 16) >> 2));
    }
  }
  if (ROLE == 0 && valid) {
    #pragma unroll
    for (int tl = 0; tl < 4; ++tl)
      x0c[tl] = *(const u64t*)&X0b[((size_t)vb * Tdim + 0) * Hdim + nvb + tl * 16];
  }

  #pragma unroll 1
  for (int t = 0; t < Tdim; t += 2) {
    REC_STEP(t, xv);
    REC_STEP(t + 1, xw);
  }
}

// X1 helper: X1[t] = Wih1 . h0[t] + b_ih1 + b_hh1, t stride NHELP.
// All 16 h-fragment pairs issued in one flight; weights: kb0-11 streamed from
// L2 in rolling 4-kb batches, kb12-15 in LDS.
__device__ void helper_role(const u16* __restrict__ Wb, const float* __restrict__ bi1,
                            const float* __restrict__ bi2, const u64t* __restrict__ H0g,
                            u64t* __restrict__ X1g, int hid, char* smem)
{
  u16* wlds = (u16*)smem;
  float* blds = (float*)(smem + 131072);
  const int tid = threadIdx.x;
  const int l = tid & 63, wv = tid >> 6;
  const int nb = wv * 64;
  const int frow = l & 15, fk = (l >> 4) << 3;
  const int vb = l & 15, vg = l >> 4;
  const bool valid = vb < 4;
  const int nvb = nb + vg * 4;

  #pragma unroll
  for (int tl = 0; tl < 4; ++tl)
    #pragma unroll
    for (int kbl = 0; kbl < 4; ++kbl) {
      bf16x8 f = *(const bf16x8*)&Wb[(size_t)(nb + tl * 16 + frow) * Hdim + (12 + kbl) * 32 + fk];
      *(bf16x8*)&wlds[(((wv * 4 + tl) * 4 + kbl) << 9) + l * 8] = f;
    }
  for (int i = tid; i < Hdim; i += 512) blds[i] = bi1[i] + bi2[i];
  __syncthreads();

  u64t fa[8], fb[8], ga[8], gb[8];
  #pragma unroll
  for (int j = 0; j < 8; ++j) { fa[j] = 0; fb[j] = 0; ga[j] = 0; gb[j] = 0; }

  #pragma unroll 1
  for (int t = hid; t < Tdim; t += NHELP) {
    const size_t tb = (size_t)t * 2048 + (size_t)vb * 512;
    if (valid) {   // one flight: all 16 fragment pairs
      #pragma unroll
      for (int kb = 0; kb < 8; ++kb) {
        const u64t* p = H0g + ((tb + kb * 32 + fk) >> 2);
        fa[kb] = al64(p); fb[kb] = al64(p + 1);
      }
      #pragma unroll
      for (int kb = 0; kb < 8; ++kb) {
        const u64t* p = H0g + ((tb + (8 + kb) * 32 + fk) >> 2);
        ga[kb] = al64(p); gb[kb] = al64(p + 1);
      }
    }
    bf16x8 wsA[4][4], wsB[4][4];
    #pragma unroll
    for (int tl = 0; tl < 4; ++tl)
      #pragma unroll
      for (int kb = 0; kb < 4; ++kb) {
        wsA[tl][kb] = *(const bf16x8*)&Wb[(size_t)(nb + tl * 16 + frow) * Hdim + kb * 32 + fk];
        wsB[tl][kb] = *(const bf16x8*)&Wb[(size_t)(nb + tl * 16 + frow) * Hdim + (4 + kb) * 32 + fk];
      }
    if (valid) {
      #pragma unroll
      for (int kb = 0; kb < 8; ++kb) {
        const u64t* p = H0g + ((tb + kb * 32 + fk) >> 2);
        while (bad64(fa[kb])) fa[kb] = al64(p);
        while (bad64(fb[kb])) fb[kb] = al64(p + 1);
      }
    }
    f32x4 acc[4];
    #pragma unroll
    for (int q = 0; q < 4; ++q) acc[q] = f32x4{0.f, 0.f, 0.f, 0.f};
    #pragma unroll
    for (int kb = 0; kb < 4; ++kb) {
      const bf16x8 hf = cast8(fa[kb], fb[kb]);
      #pragma unroll
      for (int tl = 0; tl < 4; ++tl)
        acc[tl] = __builtin_amdgcn_mfma_f32_16x16x32_bf16(wsA[tl][kb], hf, acc[tl], 0, 0, 0);
    }
    bf16x8 wsC[4][4];
    #pragma unroll
    for (int tl = 0; tl < 4; ++tl)
      #pragma unroll
      for (int kb = 0; kb < 4; ++kb)
        wsC[tl][kb] = *(const bf16x8*)&Wb[(size_t)(nb + tl * 16 + frow) * Hdim + (8 + kb) * 32 + fk];
    #pragma unroll
    for (int kb = 0; kb < 4; ++kb) {
      const bf16x8 hf = cast8(fa[4 + kb], fb[4 + kb]);
      #pragma unroll
      for (int tl = 0; tl < 4; ++tl)
        acc[tl] = __builtin_amdgcn_mfma_f32_16x16x32_bf16(wsB[tl][kb], hf, acc[tl], 0, 0, 0);
    }
    if (valid) {
      #pragma unroll
      for (int kb = 0; kb < 8; ++kb) {
        const u64t* p = H0g + ((tb + (8 + kb) * 32 + fk) >> 2);
        while (bad64(ga[kb])) ga[kb] = al64(p);
        while (bad64(gb[kb])) gb[kb] = al64(p + 1);
      }
    }
    #pragma unroll
    for (int kb = 0; kb < 4; ++kb) {
      const bf16x8 hf = cast8(ga[kb], gb[kb]);
      #pragma unroll
      for (int tl = 0; tl < 4; ++tl)
        acc[tl] = __builtin_amdgcn_mfma_f32_16x16x32_bf16(wsC[tl][kb], hf, acc[tl], 0, 0, 0);
    }
    #pragma unroll
    for (int kbl = 0; kbl < 4; ++kbl) {
      const bf16x8 hf = cast8(ga[4 + kbl], gb[4 + kbl]);
      #pragma unroll
      for (int tl = 0; tl < 4; ++tl) {
        const bf16x8 wl = *(const bf16x8*)&wlds[(((wv * 4 + tl) * 4 + kbl) << 9) + l * 8];
        acc[tl] = __builtin_amdgcn_mfma_f32_16x16x32_bf16(wl, hf, acc[tl], 0, 0, 0);
      }
    }
    if (valid) {
      #pragma unroll
      for (int tl = 0; tl < 4; ++tl) {
        const int n = nvb + tl * 16;
        const float4 bs = *(const float4*)&blds[n];
        const u64t pk = pack4(acc[tl][0] + bs.x, acc[tl][1] + bs.y,
                              acc[tl][2] + bs.z, acc[tl][3] + bs.w);
        as64(X1g + (((size_t)t * 2048 + vb * 512 + n) >> 2), pk);
      }
    }
  }
}

__global__ __launch_bounds__(512, 2) void k_scan(
    const u16* __restrict__ X0b, const u16* __restrict__ Wihb,
    const u16* __restrict__ Whhb, const float* __restrict__ b_ih,
    const float* __restrict__ b_hh, u64t* __restrict__ H0g,
    u64t* __restrict__ H1g, u64t* __restrict__ X1g, float* __restrict__ hfin)
{
  __shared__ __align__(16) char smem[139520];
  const int bid = blockIdx.x;
  if (bid == 0)
    rec_role<0>(Whhb, X0b, H0g, nullptr, hfin, smem);
  else if (bid == 1)
    rec_role<1>(Whhb + Hdim * Hdim, nullptr, H1g, X1g, hfin, smem);
  else
    helper_role(Wihb + Hdim * Hdim, b_ih + Hdim, b_hh + Hdim, H0g, X1g, bid - 2, smem);
}

// ---------------- launch ----------------
extern "C" void kernel_launch(void* const* d_in, const int* in_sizes, int n_in,
                              void* d_out, int out_size, void* d_ws, size_t ws_size,
                              hipStream_t stream)
{
  const int*   x     = (const int*)d_in[0];
  const float* embed = (const float*)d_in[1];
  const float* W_ih  = (const float*)d_in[2];
  const float* b_ih  = (const float*)d_in[3];
  const float* W_hh  = (const float*)d_in[4];
  const float* b_hh  = (const float*)d_in[5];
  const float* W_out = (const float*)d_in[6];
  const float* b_out = (const float*)d_in[7];
  float* out = (float*)d_out;

  // workspace layout (~77 MB)
  char* ws = (char*)d_ws;
  u16* E     = (u16*)ws;                                  // 8192*512
  u16* Wihb  = E + (size_t)MROWS * Hdim;                  // 2*512*512
  u16* Whhb  = Wihb + 2 * Hdim * Hdim;                    // 2*512*512
  u16* Woutb = Whhb + 2 * Hdim * Hdim;                    // 32000*512
  u16* X0b   = Woutb + (size_t)Vdim * Hdim;               // 8192*512 bf16
  u64t* H0g  = (u64t*)(X0b + (size_t)MROWS * Hdim);       // [t][b][n] bf16, 8MB
  u64t* H1g  = H0g + (size_t)Tdim * 512;
  u64t* X1g  = H1g + (size_t)Tdim * 512;

  hipMemsetAsync(H0g, 0xFF, (size_t)Tdim * 2048 * 2, stream);
  hipMemsetAsync(X1g, 0xFF, (size_t)Tdim * 2048 * 2, stream);

  k_gather<<<MROWS * (Hdim / 4) / 256, 256, 0, stream>>>(x, embed, E);
  k_f2b<<<(2 * Hdim * Hdim / 4) / 256, 256, 0, stream>>>(W_ih, Wihb, 2 * Hdim * Hdim / 4);
  k_f2b<<<(2 * Hdim * Hdim / 4) / 256, 256, 0, stream>>>(W_hh, Whhb, 2 * Hdim * Hdim / 4);
  k_f2b<<<((size_t)Vdim * Hdim / 4) / 256, 256, 0, stream>>>(W_out, Woutb, Vdim * Hdim / 4);

  // X0 = E @ Wih0^T + b_ih0 + b_hh0 -> bf16 row-major [b*T+t][n]
  k_gemm<<<(MROWS / 128) * (Hdim / 128), 256, 0, stream>>>(
      E, Wihb, (void*)X0b, b_ih, b_hh, MROWS, Hdim, Hdim, Hdim / 128, 0, 1);

  float* hfin = out + (size_t)MROWS * Vdim;
  k_scan<<<2 + NHELP, 512, 0, stream>>>(X0b, Wihb, Whhb, b_ih, b_hh,
                                        H0g, H1g, X1g, hfin);

  // out = H1 @ Wout^T + b_out   (A in [t][b][n] layout -> aperm=1, fp32 out)
  k_gemm<<<(MROWS / 128) * (Vdim / 128), 256, 0, stream>>>(
      (const u16*)H1g, Woutb, out, b_out, nullptr, MROWS, Vdim, Hdim, Vdim / 128, 1, 0);
}